// Round 4
// baseline (1076.050 us; speedup 1.0000x reference)
//
#include <hip/hip_runtime.h>
#include <hip/hip_bf16.h>
#include <cstdint>
#include <cstddef>

using bf16 = __hip_bfloat16;

typedef __attribute__((ext_vector_type(8))) short short8;     // bf16x8 MFMA A/B frag
typedef __attribute__((ext_vector_type(16))) float f32x16;    // 32x32 MFMA C/D frag
typedef __attribute__((ext_vector_type(4))) unsigned short us4;

static constexpr int Bb = 4, Ss = 2048, Hh = 2048, Ii = 8192, Gg = 128;
static constexpr int Mm = Bb * Ss;   // 8192 tokens

#define MEMFENCE() asm volatile("" ::: "memory")

// ---------------------------------------------------------------------------
// 1-bit group quantization: wq = sign(w) * mean(|w|) per contiguous 128-group.
// ---------------------------------------------------------------------------
__global__ void quant_onebit(const float* __restrict__ w, bf16* __restrict__ wq,
                             int ngroups) {
  int gid = blockIdx.x * 4 + (threadIdx.x >> 6);
  if (gid >= ngroups) return;
  int lane = threadIdx.x & 63;
  size_t base = (size_t)gid * Gg + (size_t)lane * 2;
  float2 v = *(const float2*)(w + base);
  float s = fabsf(v.x) + fabsf(v.y);
#pragma unroll
  for (int m = 32; m >= 1; m >>= 1) s += __shfl_xor(s, m);
  float scale = s * (1.0f / 128.0f);
  float q0 = (v.x > 0.f) ? scale : ((v.x < 0.f) ? -scale : 0.f);
  float q1 = (v.y > 0.f) ? scale : ((v.y < 0.f) ? -scale : 0.f);
  unsigned int p =
      (unsigned int)__builtin_bit_cast(unsigned short, __float2bfloat16(q0)) |
      ((unsigned int)__builtin_bit_cast(unsigned short, __float2bfloat16(q1)) << 16);
  *(unsigned int*)(wq + base) = p;
}

__global__ void cast_f32_bf16(const float* __restrict__ in, bf16* __restrict__ out,
                              size_t n4) {
  size_t i = (size_t)blockIdx.x * blockDim.x + threadIdx.x;
  if (i >= n4) return;
  float4 v = *(const float4*)(in + i * 4);
  us4 o;
  o.x = __builtin_bit_cast(unsigned short, __float2bfloat16(v.x));
  o.y = __builtin_bit_cast(unsigned short, __float2bfloat16(v.y));
  o.z = __builtin_bit_cast(unsigned short, __float2bfloat16(v.z));
  o.w = __builtin_bit_cast(unsigned short, __float2bfloat16(v.w));
  *(us4*)(out + i * 4) = o;
}

// ---------------------------------------------------------------------------
// 256-row GEMM, mfma_f32_32x32x16_bf16, BK=64 split into 4 k-slices of 16.
// LDS: buf[2] x { A[4 slices][256 rows][32B] ; B[4 slices][256 rows][32B] }.
// Slice-granular staging (2 gload_lds/phase) + uniform counted vmcnt(6);
// ds_reads pre-barrier, 1 barrier/phase, setprio around 8-MFMA cluster.
// DUAL: B = two 128-col panels (gate/up), silu-combine epilogue -> bf16.
// ---------------------------------------------------------------------------
__device__ __forceinline__ void gload16(const bf16* g, char* l) {
  __builtin_amdgcn_global_load_lds(
      (const __attribute__((address_space(1))) void*)g,
      (__attribute__((address_space(3))) void*)l, 16, 0, 0);
}

template <bool DUAL>
__global__ __launch_bounds__(512, 2)
void gemm_bt8(const bf16* __restrict__ A,   // [M,K]
              const bf16* __restrict__ B0,  // [N,K]
              const bf16* __restrict__ B1,  // [N,K] (DUAL)
              bf16* __restrict__ OutBf,     // [M,N] (DUAL)
              float* __restrict__ OutF,     // [M,N] (!DUAL)
              int M, int N, int K) {
  constexpr int BM = 256, BN = DUAL ? 128 : 256;
  extern __shared__ char smem[];            // 2 x 64 KiB

  const int tid = threadIdx.x;
  const int wid = tid >> 6;                 // 0..7
  const int lane = tid & 63;
  const int wr = wid >> 2;                  // 0..1 row half (128 rows)
  const int wc = wid & 3;                   // 0..3 col quarter
  const int l31 = lane & 31;
  const int lh = lane >> 5;                 // k-half within 16-k slice

  // XCD-bijective swizzle (grids are multiples of 8)
  const int nbx = N / BN;
  const int nwg = (int)gridDim.x;
  const int cpx = nwg >> 3;
  const int wg = (int)blockIdx.x;
  const int swz = (wg & 7) * cpx + (wg >> 3);
  const int m0 = (swz / nbx) * BM;
  const int n0 = (swz % nbx) * BN;

  const int NT = K / 64;

  // ---- staging sources: thread u covers (row = u>>1, 16B half = u&1) of a
  // [256 row][32 B] slice; dest is linear (wave base + lane*16).
  const int srow = tid >> 1;
  const int se = (tid & 1) * 8;             // bf16 elem offset within slice row
  const bf16* srcA = A + (size_t)(m0 + srow) * K + se;
  const bf16* srcB;
  if constexpr (DUAL)
    srcB = (srow < 128 ? B0 + (size_t)(n0 + srow) * K
                       : B1 + (size_t)(n0 + srow - 128) * K) + se;
  else
    srcB = B0 + (size_t)(n0 + srow) * K + se;
  const int dOff = wid * 1024;

  auto stage = [&](int t, int ks) {
    const int koff = t * 64 + ks * 16;
    char* base = smem + (size_t)(t & 1) * 65536 + ks * 8192;
    gload16(srcA + koff, base + dOff);
    gload16(srcB + koff, base + 32768 + dOff);
  };

  // ---- frag read byte-offsets within a slice (inherently bank-balanced)
  const int aOff = (wr * 128 + l31) * 32 + lh * 16;
  const int bRow = DUAL ? (wc * 32 + l31) : (wc * 64 + l31);
  const int bOff = bRow * 32 + lh * 16;
  const int b1Off = DUAL ? 4096 : 1024;     // panel1 (+128 rows) | nf1 (+32 rows)

  const f32x16 vzero = {0.f};
  f32x16 acc0[4], acc1[4];
#pragma unroll
  for (int mf = 0; mf < 4; ++mf) { acc0[mf] = vzero; acc1[mf] = vzero; }

  // ---- prologue: stage tile0 slices 0..3 (8 loads), wait slice0 cross-wave
#pragma unroll
  for (int ks = 0; ks < 4; ++ks) stage(0, ks);
  asm volatile("s_waitcnt vmcnt(6)" ::: "memory");
  __builtin_amdgcn_s_barrier();
  MEMFENCE();

  for (int t = 0; t < NT; ++t) {
    const char* buf = smem + (size_t)(t & 1) * 65536;
#pragma unroll
    for (int ks = 0; ks < 4; ++ks) {
      const char* As_ = buf + ks * 8192;
      const char* Bs_ = buf + 32768 + ks * 8192;
      short8 fa[4], fb0, fb1;
#pragma unroll
      for (int mf = 0; mf < 4; ++mf)
        fa[mf] = *(const short8*)(As_ + aOff + mf * 1024);
      fb0 = *(const short8*)(Bs_ + bOff);
      fb1 = *(const short8*)(Bs_ + bOff + b1Off);
      MEMFENCE();
      if (t + 1 < NT) stage(t + 1, ks);
      // vmcnt covers slice(t, ks+1) for the post-barrier reads of next phase
      if (t + 1 < NT)     asm volatile("s_waitcnt vmcnt(6)" ::: "memory");
      else if (ks == 0)   asm volatile("s_waitcnt vmcnt(4)" ::: "memory");
      else if (ks == 1)   asm volatile("s_waitcnt vmcnt(2)" ::: "memory");
      else if (ks == 2)   asm volatile("s_waitcnt vmcnt(0)" ::: "memory");
      __builtin_amdgcn_s_barrier();
      MEMFENCE();
      __builtin_amdgcn_s_setprio(1);
#pragma unroll
      for (int mf = 0; mf < 4; ++mf) {
        acc0[mf] = __builtin_amdgcn_mfma_f32_32x32x16_bf16(
            fa[mf], fb0, acc0[mf], 0, 0, 0);
        acc1[mf] = __builtin_amdgcn_mfma_f32_32x32x16_bf16(
            fa[mf], fb1, acc1[mf], 0, 0, 0);
      }
      __builtin_amdgcn_s_setprio(0);
    }
  }

  // ---- epilogue: 32x32 C/D layout col=lane&31, row=(r&3)+8*(r>>2)+4*(lane>>5)
#pragma unroll
  for (int mf = 0; mf < 4; ++mf)
#pragma unroll
    for (int r = 0; r < 16; ++r) {
      const int row = m0 + wr * 128 + mf * 32 + (r & 3) + 8 * (r >> 2) + 4 * lh;
      if constexpr (DUAL) {
        const int col = n0 + wc * 32 + l31;
        float g = acc0[mf][r];
        float u = acc1[mf][r];
        OutBf[(size_t)row * N + col] =
            __float2bfloat16(g / (1.0f + expf(-g)) * u);
      } else {
        const int col = n0 + wc * 64 + l31;
        OutF[(size_t)row * N + col] = acc0[mf][r];
        OutF[(size_t)row * N + col + 32] = acc1[mf][r];
      }
    }
}

// ---------------------------------------------------------------------------
extern "C" void kernel_launch(void* const* d_in, const int* in_sizes, int n_in,
                              void* d_out, int out_size, void* d_ws, size_t ws_size,
                              hipStream_t stream) {
  const float* x = (const float*)d_in[0];
  const float* wg = (const float*)d_in[1];
  const float* wu = (const float*)d_in[2];
  const float* wd = (const float*)d_in[3];
  float* out = (float*)d_out;

  char* ws = (char*)d_ws;
  bf16* xq = (bf16*)(ws + 0);
  bf16* wgq = (bf16*)(ws + (size_t)33554432);
  bf16* wuq = (bf16*)(ws + (size_t)67108864);
  bf16* hbuf = (bf16*)(ws + (size_t)100663296);
  bf16* wdq = xq;  // xq dead after GEMM1

  auto* kDual = gemm_bt8<true>;
  auto* kSingle = gemm_bt8<false>;
  (void)hipFuncSetAttribute((const void*)kDual,
                            hipFuncAttributeMaxDynamicSharedMemorySize, 131072);
  (void)hipFuncSetAttribute((const void*)kSingle,
                            hipFuncAttributeMaxDynamicSharedMemorySize, 131072);

  const int ngW = (Ii * Hh) / Gg;
  quant_onebit<<<ngW / 4, 256, 0, stream>>>(wg, wgq, ngW);
  quant_onebit<<<ngW / 4, 256, 0, stream>>>(wu, wuq, ngW);

  const size_t n4 = (size_t)Mm * Hh / 4;
  cast_f32_bf16<<<(unsigned)((n4 + 255) / 256), 256, 0, stream>>>(x, xq, n4);

  // GEMM1 fused: h = silu(x@wgq^T) * (x@wuq^T)  [M=8192, N=8192, K=2048]
  kDual<<<(Mm / 256) * (Ii / 128), 512, 131072, stream>>>(
      xq, wgq, wuq, hbuf, nullptr, Mm, Ii, Hh);

  quant_onebit<<<ngW / 4, 256, 0, stream>>>(wd, wdq, ngW);

  // GEMM2: out = h @ wdq^T  [M=8192, N=2048, K=8192]
  kSingle<<<(Mm / 256) * (Hh / 256), 512, 131072, stream>>>(
      hbuf, wdq, nullptr, nullptr, out, Mm, Hh, Ii);
}

// Round 5
// 867.060 us; speedup vs baseline: 1.2410x; 1.2410x over previous
//
#include <hip/hip_runtime.h>
#include <hip/hip_bf16.h>
#include <cstdint>
#include <cstddef>

using bf16 = __hip_bfloat16;

typedef __attribute__((ext_vector_type(8))) short short8;   // bf16x8 MFMA A/B frag
typedef __attribute__((ext_vector_type(4))) float f32x4;    // MFMA C/D frag
typedef __attribute__((ext_vector_type(4))) unsigned short us4;

static constexpr int Bb = 4, Ss = 2048, Hh = 2048, Ii = 8192, Gg = 128;
static constexpr int Mm = Bb * Ss;   // 8192 tokens

#define MEMFENCE() asm volatile("" ::: "memory")
#define BARRIER() do { MEMFENCE(); __builtin_amdgcn_s_barrier(); MEMFENCE(); } while (0)

// ---------------------------------------------------------------------------
// 1-bit group quantization: wq = sign(w) * mean(|w|) per contiguous 128-group.
// ---------------------------------------------------------------------------
__global__ void quant_onebit(const float* __restrict__ w, bf16* __restrict__ wq,
                             int ngroups) {
  int gid = blockIdx.x * 4 + (threadIdx.x >> 6);
  if (gid >= ngroups) return;
  int lane = threadIdx.x & 63;
  size_t base = (size_t)gid * Gg + (size_t)lane * 2;
  float2 v = *(const float2*)(w + base);
  float s = fabsf(v.x) + fabsf(v.y);
#pragma unroll
  for (int m = 32; m >= 1; m >>= 1) s += __shfl_xor(s, m);
  float scale = s * (1.0f / 128.0f);
  float q0 = (v.x > 0.f) ? scale : ((v.x < 0.f) ? -scale : 0.f);
  float q1 = (v.y > 0.f) ? scale : ((v.y < 0.f) ? -scale : 0.f);
  unsigned int p =
      (unsigned int)__builtin_bit_cast(unsigned short, __float2bfloat16(q0)) |
      ((unsigned int)__builtin_bit_cast(unsigned short, __float2bfloat16(q1)) << 16);
  *(unsigned int*)(wq + base) = p;
}

__global__ void cast_f32_bf16(const float* __restrict__ in, bf16* __restrict__ out,
                              size_t n4) {
  size_t i = (size_t)blockIdx.x * blockDim.x + threadIdx.x;
  if (i >= n4) return;
  float4 v = *(const float4*)(in + i * 4);
  us4 o;
  o.x = __builtin_bit_cast(unsigned short, __float2bfloat16(v.x));
  o.y = __builtin_bit_cast(unsigned short, __float2bfloat16(v.y));
  o.z = __builtin_bit_cast(unsigned short, __float2bfloat16(v.z));
  o.w = __builtin_bit_cast(unsigned short, __float2bfloat16(v.w));
  *(us4*)(out + i * 4) = o;
}

// ---------------------------------------------------------------------------
// 256-row GEMM, BK=64 (2 k-slices of 32), 2-deep dbuf, 4 phases/tile.
// Template rhythm (m201): per phase {ds_read frags ; 1 stage-call ;
// [slice-boundary vmcnt(4)] ; barrier ; setprio(1) 16xMFMA setprio(0) ;
// barrier}. XOR slot-swizzle (verified 0 conflicts), both-sides applied.
// DUAL: fused gate/up (two 128-col B panels) + silu epilogue -> bf16.
// ---------------------------------------------------------------------------
__device__ __forceinline__ void gload16(const bf16* g, char* l) {
  __builtin_amdgcn_global_load_lds(
      (const __attribute__((address_space(1))) void*)g,
      (__attribute__((address_space(3))) void*)l, 16, 0, 0);
}

// Swizzled frag read: row stride 64 B (4 x 16 B slots), phys slot = s ^ (row>>1)&3.
__device__ __forceinline__ short8 lfrag(const char* part, int row, int s) {
  return *(const short8*)(part + row * 64 + (((s ^ (row >> 1)) & 3) << 4));
}

template <bool DUAL>
__global__ __launch_bounds__(512, 2)
void gemm_bt8(const bf16* __restrict__ A,   // [M,K]
              const bf16* __restrict__ B0,  // [N,K]
              const bf16* __restrict__ B1,  // [N,K] (DUAL)
              bf16* __restrict__ OutBf,     // [M,N] (DUAL)
              float* __restrict__ OutF,     // [M,N] (!DUAL)
              int M, int N, int K) {
  constexpr int BM = 256, BN = DUAL ? 128 : 256;
  constexpr int NF = DUAL ? 2 : 4;        // n-frags per wave (per matrix)
  // LDS: buf[2] x slice[2] x (A 16K + B 16K) = 131072 B
  extern __shared__ char smem[];

  const int tid = threadIdx.x;
  const int wid = tid >> 6;               // 0..7
  const int lane = tid & 63;
  const int wr = wid >> 2;                // 0..1 row half
  const int wc = wid & 3;                 // 0..3 col quarter
  const int lrow = lane & 15;
  const int ks = lane >> 4;               // 16B slot 0..3 within 64B k-slice row

  // XCD-bijective swizzle (grids are multiples of 8)
  const int nbx = N / BN;
  const int nwg = (int)gridDim.x;
  const int cpx = nwg >> 3;
  const int wg = (int)blockIdx.x;
  const int swz = (wg & 7) * cpx + (wg >> 3);
  const int m0 = (swz / nbx) * BM;
  const int n0 = (swz % nbx) * BN;

  const int NT = K / 64;

  // ---- staging: dest linear (wave base + lane*16); source slot
  // inverse-swizzled so linear write + swizzled read compose to identity.
  const int srow = tid >> 2;                          // 0..127
  const int slog8 = (((tid & 3) ^ ((tid >> 3) & 3)) << 3);
  const bf16* pA0 = A + (size_t)(m0 + srow) * K + slog8;
  const bf16* pA1 = pA0 + (size_t)128 * K;
  const bf16* pB0 = B0 + (size_t)(n0 + srow) * K + slog8;
  const bf16* pB1 = DUAL ? (B1 + (size_t)(n0 + srow) * K + slog8)
                         : (pB0 + (size_t)128 * K);
  const int dA = wid * 1024;

  auto stageA = [&](int t, int p) {       // 2 loads: A rows 0..255, slice p
    char* b = smem + (size_t)(t & 1) * 65536 + p * 32768;
    const int koff = t * 64 + p * 32;
    gload16(pA0 + koff, b + dA);
    gload16(pA1 + koff, b + 8192 + dA);
  };
  auto stageB = [&](int t, int p) {       // 2 loads: B panel(s), slice p
    char* b = smem + (size_t)(t & 1) * 65536 + p * 32768 + 16384;
    const int koff = t * 64 + p * 32;
    gload16(pB0 + koff, b + dA);
    gload16(pB1 + koff, b + 8192 + dA);
  };

  const f32x4 vzero = {0.f, 0.f, 0.f, 0.f};
  f32x4 acc0[8][NF];
  f32x4 acc1[DUAL ? 8 : 1][NF];
#pragma unroll
  for (int mf = 0; mf < 8; ++mf)
#pragma unroll
    for (int nf = 0; nf < NF; ++nf) {
      acc0[mf][nf] = vzero;
      if constexpr (DUAL) acc1[mf][nf] = vzero;
    }

  // ---- prologue: stage tile0 (order sA0,sB0,sA1,sB1 = 8 loads), wait slice0
  stageA(0, 0); stageB(0, 0);
  stageA(0, 1); stageB(0, 1);
  asm volatile("s_waitcnt vmcnt(4)" ::: "memory");
  __builtin_amdgcn_s_barrier();
  MEMFENCE();

  short8 fa[4], fb0[NF], fb1[DUAL ? NF : 1];

  for (int t = 0; t < NT; ++t) {
    const char* buf = smem + (size_t)(t & 1) * 65536;
#pragma unroll
    for (int p = 0; p < 2; ++p) {
      const char* Ap = buf + p * 32768;
      const char* Bp = Ap + 16384;

      // ===== phase (p,0): reads (B + A[m0-3]) PRE-barrier | stage A(t+1,p)
      if constexpr (DUAL) {
#pragma unroll
        for (int nf = 0; nf < 2; ++nf) {
          fb0[nf] = lfrag(Bp, wc * 32 + nf * 16 + lrow, ks);
          fb1[nf] = lfrag(Bp + 8192, wc * 32 + nf * 16 + lrow, ks);
        }
      } else {
#pragma unroll
        for (int nf = 0; nf < 4; ++nf)
          fb0[nf] = lfrag(Bp, wc * 64 + nf * 16 + lrow, ks);
      }
#pragma unroll
      for (int i = 0; i < 4; ++i)
        fa[i] = lfrag(Ap, wr * 128 + i * 16 + lrow, ks);
      if (t + 1 < NT) stageA(t + 1, p);
      BARRIER();                               // #1: reads enqueued block-wide
      __builtin_amdgcn_s_setprio(1);
#pragma unroll
      for (int i = 0; i < 4; ++i)
#pragma unroll
        for (int nf = 0; nf < NF; ++nf) {
          acc0[i][nf] = __builtin_amdgcn_mfma_f32_16x16x32_bf16(
              fa[i], fb0[nf], acc0[i][nf], 0, 0, 0);
          if constexpr (DUAL)
            acc1[i][nf] = __builtin_amdgcn_mfma_f32_16x16x32_bf16(
                fa[i], fb1[nf], acc1[i][nf], 0, 0, 0);
        }
      __builtin_amdgcn_s_setprio(0);
      BARRIER();                               // #2

      // ===== phase (p,1): reads A[m4-7] PRE-barrier | stage B(t+1,p) |
      // slice-boundary counted wait (covers next slice, never drains mid-loop)
#pragma unroll
      for (int i = 0; i < 4; ++i)
        fa[i] = lfrag(Ap, wr * 128 + 64 + i * 16 + lrow, ks);
      if (t + 1 < NT) {
        stageB(t + 1, p);
        asm volatile("s_waitcnt vmcnt(4)" ::: "memory");
      } else if (p == 0) {
        asm volatile("s_waitcnt vmcnt(0)" ::: "memory");
      }
      BARRIER();                               // #1
      __builtin_amdgcn_s_setprio(1);
#pragma unroll
      for (int i = 0; i < 4; ++i)
#pragma unroll
        for (int nf = 0; nf < NF; ++nf) {
          acc0[4 + i][nf] = __builtin_amdgcn_mfma_f32_16x16x32_bf16(
              fa[i], fb0[nf], acc0[4 + i][nf], 0, 0, 0);
          if constexpr (DUAL)
            acc1[4 + i][nf] = __builtin_amdgcn_mfma_f32_16x16x32_bf16(
                fa[i], fb1[nf], acc1[4 + i][nf], 0, 0, 0);
        }
      __builtin_amdgcn_s_setprio(0);
      BARRIER();                               // #2
    }
  }

  // ---- epilogue: C/D layout col=lane&15, row=(lane>>4)*4+j
  const int crow0 = (lane >> 4) * 4;
  const int ccol = lane & 15;
#pragma unroll
  for (int mf = 0; mf < 8; ++mf)
#pragma unroll
    for (int nf = 0; nf < NF; ++nf)
#pragma unroll
      for (int j = 0; j < 4; ++j) {
        const int row = m0 + wr * 128 + mf * 16 + crow0 + j;
        if constexpr (DUAL) {
          const int col = n0 + wc * 32 + nf * 16 + ccol;
          float g = acc0[mf][nf][j];
          float u = acc1[mf][nf][j];
          OutBf[(size_t)row * N + col] =
              __float2bfloat16(g / (1.0f + expf(-g)) * u);
        } else {
          const int col = n0 + wc * 64 + nf * 16 + ccol;
          OutF[(size_t)row * N + col] = acc0[mf][nf][j];
        }
      }
}

// ---------------------------------------------------------------------------
extern "C" void kernel_launch(void* const* d_in, const int* in_sizes, int n_in,
                              void* d_out, int out_size, void* d_ws, size_t ws_size,
                              hipStream_t stream) {
  const float* x = (const float*)d_in[0];
  const float* wg = (const float*)d_in[1];
  const float* wu = (const float*)d_in[2];
  const float* wd = (const float*)d_in[3];
  float* out = (float*)d_out;

  char* ws = (char*)d_ws;
  bf16* xq = (bf16*)(ws + 0);
  bf16* wgq = (bf16*)(ws + (size_t)33554432);
  bf16* wuq = (bf16*)(ws + (size_t)67108864);
  bf16* hbuf = (bf16*)(ws + (size_t)100663296);
  bf16* wdq = xq;  // xq dead after GEMM1

  auto* kDual = gemm_bt8<true>;
  auto* kSingle = gemm_bt8<false>;
  (void)hipFuncSetAttribute((const void*)kDual,
                            hipFuncAttributeMaxDynamicSharedMemorySize, 131072);
  (void)hipFuncSetAttribute((const void*)kSingle,
                            hipFuncAttributeMaxDynamicSharedMemorySize, 131072);

  const int ngW = (Ii * Hh) / Gg;
  quant_onebit<<<ngW / 4, 256, 0, stream>>>(wg, wgq, ngW);
  quant_onebit<<<ngW / 4, 256, 0, stream>>>(wu, wuq, ngW);

  const size_t n4 = (size_t)Mm * Hh / 4;
  cast_f32_bf16<<<(unsigned)((n4 + 255) / 256), 256, 0, stream>>>(x, xq, n4);

  // GEMM1 fused: h = silu(x@wgq^T) * (x@wuq^T)  [M=8192, N=8192, K=2048]
  kDual<<<(Mm / 256) * (Ii / 128), 512, 131072, stream>>>(
      xq, wgq, wuq, hbuf, nullptr, Mm, Ii, Hh);

  quant_onebit<<<ngW / 4, 256, 0, stream>>>(wd, wdq, ngW);

  // GEMM2: out = h @ wdq^T  [M=8192, N=2048, K=8192]
  kSingle<<<(Mm / 256) * (Hh / 256), 512, 131072, stream>>>(
      hbuf, wdq, nullptr, nullptr, out, Mm, Hh, Ii);
}

// Round 6
// 818.510 us; speedup vs baseline: 1.3146x; 1.0593x over previous
//
#include <hip/hip_runtime.h>
#include <hip/hip_bf16.h>
#include <cstdint>
#include <cstddef>

using bf16 = __hip_bfloat16;

typedef __attribute__((ext_vector_type(8))) short short8;   // bf16x8 MFMA A/B frag
typedef __attribute__((ext_vector_type(4))) float f32x4;    // MFMA C/D frag
typedef __attribute__((ext_vector_type(4))) unsigned short us4;

static constexpr int Bb = 4, Ss = 2048, Hh = 2048, Ii = 8192, Gg = 128;
static constexpr int Mm = Bb * Ss;   // 8192 tokens

#define MEMFENCE() asm volatile("" ::: "memory")
#define BARRIER() do { MEMFENCE(); __builtin_amdgcn_s_barrier(); MEMFENCE(); } while (0)

// ---------------------------------------------------------------------------
// 1-bit group quantization: wq = sign(w) * mean(|w|) per contiguous 128-group.
// ---------------------------------------------------------------------------
__global__ void quant_onebit(const float* __restrict__ w, bf16* __restrict__ wq,
                             int ngroups) {
  int gid = blockIdx.x * 4 + (threadIdx.x >> 6);
  if (gid >= ngroups) return;
  int lane = threadIdx.x & 63;
  size_t base = (size_t)gid * Gg + (size_t)lane * 2;
  float2 v = *(const float2*)(w + base);
  float s = fabsf(v.x) + fabsf(v.y);
#pragma unroll
  for (int m = 32; m >= 1; m >>= 1) s += __shfl_xor(s, m);
  float scale = s * (1.0f / 128.0f);
  float q0 = (v.x > 0.f) ? scale : ((v.x < 0.f) ? -scale : 0.f);
  float q1 = (v.y > 0.f) ? scale : ((v.y < 0.f) ? -scale : 0.f);
  unsigned int p =
      (unsigned int)__builtin_bit_cast(unsigned short, __float2bfloat16(q0)) |
      ((unsigned int)__builtin_bit_cast(unsigned short, __float2bfloat16(q1)) << 16);
  *(unsigned int*)(wq + base) = p;
}

__global__ void cast_f32_bf16(const float* __restrict__ in, bf16* __restrict__ out,
                              size_t n4) {
  size_t i = (size_t)blockIdx.x * blockDim.x + threadIdx.x;
  if (i >= n4) return;
  float4 v = *(const float4*)(in + i * 4);
  us4 o;
  o.x = __builtin_bit_cast(unsigned short, __float2bfloat16(v.x));
  o.y = __builtin_bit_cast(unsigned short, __float2bfloat16(v.y));
  o.z = __builtin_bit_cast(unsigned short, __float2bfloat16(v.z));
  o.w = __builtin_bit_cast(unsigned short, __float2bfloat16(v.w));
  *(us4*)(out + i * 4) = o;
}

// ---------------------------------------------------------------------------
// 256-row GEMM, BK=64 (2 k-slices of 32), 2-deep dbuf, 4 phases/tile.
// R3 rhythm (best measured): per slice {vmcnt(4); barrier; reads; stage;
// setprio MFMA; barrier; reads; stage; setprio MFMA}. XOR slot-swizzle
// (verified 0 conflicts), both-sides applied.
// NEW (R6): chunked-N locality mapping — each XCD's contiguous block range
// covers CN=8 n-blocks x all m-blocks, keeping the B-chunk (8 MB) L2/L3-hot
// instead of sweeping the full 64 MB B per A-strip.
// DUAL: fused gate/up (two 128-col B panels) + silu epilogue -> bf16.
// ---------------------------------------------------------------------------
__device__ __forceinline__ void gload16(const bf16* g, char* l) {
  __builtin_amdgcn_global_load_lds(
      (const __attribute__((address_space(1))) void*)g,
      (__attribute__((address_space(3))) void*)l, 16, 0, 0);
}

// Swizzled frag read: row stride 64 B (4 x 16 B slots), phys slot = s ^ (row>>1)&3.
__device__ __forceinline__ short8 lfrag(const char* part, int row, int s) {
  return *(const short8*)(part + row * 64 + (((s ^ (row >> 1)) & 3) << 4));
}

template <bool DUAL>
__global__ __launch_bounds__(512, 2)
void gemm_bt8(const bf16* __restrict__ A,   // [M,K]
              const bf16* __restrict__ B0,  // [N,K]
              const bf16* __restrict__ B1,  // [N,K] (DUAL)
              bf16* __restrict__ OutBf,     // [M,N] (DUAL)
              float* __restrict__ OutF,     // [M,N] (!DUAL)
              int M, int N, int K) {
  constexpr int BM = 256, BN = DUAL ? 128 : 256;
  constexpr int NF = DUAL ? 2 : 4;        // n-frags per wave (per matrix)
  // LDS: buf[2] x slice[2] x (A 16K + B 16K) = 131072 B
  extern __shared__ char smem[];

  const int tid = threadIdx.x;
  const int wid = tid >> 6;               // 0..7
  const int lane = tid & 63;
  const int wr = wid >> 2;                // 0..1 row half
  const int wc = wid & 3;                 // 0..3 col quarter
  const int lrow = lane & 15;
  const int ks = lane >> 4;               // 16B slot 0..3 within 64B k-slice row

  // ---- locality mapping: XCD-bijective, then chunk N (CN n-blocks x all
  // m-blocks per chunk). nbx % 8 == 0 for both our shapes (64, 8).
  const int nbx = N / BN;
  const int nbm = M / BM;
  const int nwg = (int)gridDim.x;
  const int cpx = nwg >> 3;
  const int wg = (int)blockIdx.x;
  const int L = (wg & 7) * cpx + (wg >> 3);
  constexpr int CN = 8;
  const int chunk = L / (nbm * CN);
  const int within = L % (nbm * CN);
  const int m0 = (within / CN) * BM;
  const int n0 = (chunk * CN + (within % CN)) * BN;

  const int NT = K / 64;

  // ---- staging: dest linear (wave base + lane*16); source slot
  // inverse-swizzled so linear write + swizzled read compose to identity.
  const int srow = tid >> 2;                          // 0..127
  const int slog8 = (((tid & 3) ^ ((tid >> 3) & 3)) << 3);
  const bf16* pA0 = A + (size_t)(m0 + srow) * K + slog8;
  const bf16* pA1 = pA0 + (size_t)128 * K;
  const bf16* pB0 = B0 + (size_t)(n0 + srow) * K + slog8;
  const bf16* pB1 = DUAL ? (B1 + (size_t)(n0 + srow) * K + slog8)
                         : (pB0 + (size_t)128 * K);
  const int dA = wid * 1024;

  auto stageA = [&](int t, int p) {       // 2 loads: A rows 0..255, slice p
    char* b = smem + (size_t)(t & 1) * 65536 + p * 32768;
    const int koff = t * 64 + p * 32;
    gload16(pA0 + koff, b + dA);
    gload16(pA1 + koff, b + 8192 + dA);
  };
  auto stageB = [&](int t, int p) {       // 2 loads: B panel(s), slice p
    char* b = smem + (size_t)(t & 1) * 65536 + p * 32768 + 16384;
    const int koff = t * 64 + p * 32;
    gload16(pB0 + koff, b + dA);
    gload16(pB1 + koff, b + 8192 + dA);
  };

  const f32x4 vzero = {0.f, 0.f, 0.f, 0.f};
  f32x4 acc0[8][NF];
  f32x4 acc1[DUAL ? 8 : 1][NF];
#pragma unroll
  for (int mf = 0; mf < 8; ++mf)
#pragma unroll
    for (int nf = 0; nf < NF; ++nf) {
      acc0[mf][nf] = vzero;
      if constexpr (DUAL) acc1[mf][nf] = vzero;
    }

  // ---- prologue: stage tile0 (order sA0,sB0,sA1,sB1 = 8 loads)
  stageA(0, 0); stageB(0, 0);
  stageA(0, 1); stageB(0, 1);

  short8 fa[4], fb0[NF], fb1[DUAL ? NF : 1];

  for (int t = 0; t < NT; ++t) {
    const char* buf = smem + (size_t)(t & 1) * 65536;
#pragma unroll
    for (int p = 0; p < 2; ++p) {
      const char* Ap = buf + p * 32768;
      const char* Bp = Ap + 16384;

      // ===== phase (p,0): wait slice p, read B + A[mf0-3], stage A(t+1,p)
      if (p == 0 || t + 1 < NT)
        asm volatile("s_waitcnt vmcnt(4)" ::: "memory");
      else
        asm volatile("s_waitcnt vmcnt(0)" ::: "memory");
      BARRIER();
      if constexpr (DUAL) {
#pragma unroll
        for (int nf = 0; nf < 2; ++nf) {
          fb0[nf] = lfrag(Bp, wc * 32 + nf * 16 + lrow, ks);
          fb1[nf] = lfrag(Bp + 8192, wc * 32 + nf * 16 + lrow, ks);
        }
      } else {
#pragma unroll
        for (int nf = 0; nf < 4; ++nf)
          fb0[nf] = lfrag(Bp, wc * 64 + nf * 16 + lrow, ks);
      }
#pragma unroll
      for (int i = 0; i < 4; ++i)
        fa[i] = lfrag(Ap, wr * 128 + i * 16 + lrow, ks);
      if (t + 1 < NT) stageA(t + 1, p);
      __builtin_amdgcn_s_setprio(1);
#pragma unroll
      for (int i = 0; i < 4; ++i)
#pragma unroll
        for (int nf = 0; nf < NF; ++nf) {
          acc0[i][nf] = __builtin_amdgcn_mfma_f32_16x16x32_bf16(
              fa[i], fb0[nf], acc0[i][nf], 0, 0, 0);
          if constexpr (DUAL)
            acc1[i][nf] = __builtin_amdgcn_mfma_f32_16x16x32_bf16(
                fa[i], fb1[nf], acc1[i][nf], 0, 0, 0);
        }
      __builtin_amdgcn_s_setprio(0);
      BARRIER();

      // ===== phase (p,1): read A[mf4-7] (B reused), stage B(t+1,p)
#pragma unroll
      for (int i = 0; i < 4; ++i)
        fa[i] = lfrag(Ap, wr * 128 + 64 + i * 16 + lrow, ks);
      if (t + 1 < NT) stageB(t + 1, p);
      __builtin_amdgcn_s_setprio(1);
#pragma unroll
      for (int i = 0; i < 4; ++i)
#pragma unroll
        for (int nf = 0; nf < NF; ++nf) {
          acc0[4 + i][nf] = __builtin_amdgcn_mfma_f32_16x16x32_bf16(
              fa[i], fb0[nf], acc0[4 + i][nf], 0, 0, 0);
          if constexpr (DUAL)
            acc1[4 + i][nf] = __builtin_amdgcn_mfma_f32_16x16x32_bf16(
                fa[i], fb1[nf], acc1[4 + i][nf], 0, 0, 0);
        }
      __builtin_amdgcn_s_setprio(0);
    }
  }

  // ---- epilogue: C/D layout col=lane&15, row=(lane>>4)*4+j
  const int crow0 = (lane >> 4) * 4;
  const int ccol = lane & 15;
#pragma unroll
  for (int mf = 0; mf < 8; ++mf)
#pragma unroll
    for (int nf = 0; nf < NF; ++nf)
#pragma unroll
      for (int j = 0; j < 4; ++j) {
        const int row = m0 + wr * 128 + mf * 16 + crow0 + j;
        if constexpr (DUAL) {
          const int col = n0 + wc * 32 + nf * 16 + ccol;
          float g = acc0[mf][nf][j];
          float u = acc1[mf][nf][j];
          OutBf[(size_t)row * N + col] =
              __float2bfloat16(g / (1.0f + expf(-g)) * u);
        } else {
          const int col = n0 + wc * 64 + nf * 16 + ccol;
          OutF[(size_t)row * N + col] = acc0[mf][nf][j];
        }
      }
}

// ---------------------------------------------------------------------------
extern "C" void kernel_launch(void* const* d_in, const int* in_sizes, int n_in,
                              void* d_out, int out_size, void* d_ws, size_t ws_size,
                              hipStream_t stream) {
  const float* x = (const float*)d_in[0];
  const float* wg = (const float*)d_in[1];
  const float* wu = (const float*)d_in[2];
  const float* wd = (const float*)d_in[3];
  float* out = (float*)d_out;

  char* ws = (char*)d_ws;
  bf16* xq = (bf16*)(ws + 0);
  bf16* wgq = (bf16*)(ws + (size_t)33554432);
  bf16* wuq = (bf16*)(ws + (size_t)67108864);
  bf16* hbuf = (bf16*)(ws + (size_t)100663296);
  bf16* wdq = xq;  // xq dead after GEMM1

  auto* kDual = gemm_bt8<true>;
  auto* kSingle = gemm_bt8<false>;
  (void)hipFuncSetAttribute((const void*)kDual,
                            hipFuncAttributeMaxDynamicSharedMemorySize, 131072);
  (void)hipFuncSetAttribute((const void*)kSingle,
                            hipFuncAttributeMaxDynamicSharedMemorySize, 131072);

  const int ngW = (Ii * Hh) / Gg;
  quant_onebit<<<ngW / 4, 256, 0, stream>>>(wg, wgq, ngW);
  quant_onebit<<<ngW / 4, 256, 0, stream>>>(wu, wuq, ngW);

  const size_t n4 = (size_t)Mm * Hh / 4;
  cast_f32_bf16<<<(unsigned)((n4 + 255) / 256), 256, 0, stream>>>(x, xq, n4);

  // GEMM1 fused: h = silu(x@wgq^T) * (x@wuq^T)  [M=8192, N=8192, K=2048]
  kDual<<<(Mm / 256) * (Ii / 128), 512, 131072, stream>>>(
      xq, wgq, wuq, hbuf, nullptr, Mm, Ii, Hh);

  quant_onebit<<<ngW / 4, 256, 0, stream>>>(wd, wdq, ngW);

  // GEMM2: out = h @ wdq^T  [M=8192, N=2048, K=8192]
  kSingle<<<(Mm / 256) * (Hh / 256), 512, 131072, stream>>>(
      hbuf, wdq, nullptr, nullptr, out, Mm, Hh, Ii);
}